// Round 5
// baseline (84.640 us; speedup 1.0000x reference)
//
#include <hip/hip_runtime.h>

// GAT layer, N=8192, IN_F=128, OUT_F=64.
//   Wh = h@W; Wh1 = Wh@a1; Wh2 = Wh@a2
//   e[i][j] = leakyrelu(Wh1[i]+Wh2[j]); p = adj>0 ? exp(e) : 0
//   out = (P @ Wh) / rowsum(P)
// Floor: adj read = 256 MB => ~41 us @ 6.3 TB/s.
// Round 5: single change vs round 4 — per-block column-slab ROTATION
// (block b sweeps slabs (rr+b)&15) to decorrelate the chip-wide HBM
// channel phase of the 8192 synchronized row streams.

#define NN    8192
#define INF   128
#define OUTF  64
#define BM    32       // rows per block
#define RJ    512      // j per round
#define NR    (NN/RJ)  // 16 rounds
#define LOG2E 1.4426950408889634f

typedef float  f32x4 __attribute__((ext_vector_type(4)));
typedef int    i32x4 __attribute__((ext_vector_type(4)));
typedef __bf16 bf16x4 __attribute__((ext_vector_type(4)));
typedef __bf16 bf16x8 __attribute__((ext_vector_type(8)));

__device__ __forceinline__ unsigned short f2bf(float x) {
    unsigned u = __builtin_bit_cast(unsigned, x);
    return (unsigned short)((u + 0x7fffu + ((u >> 16) & 1u)) >> 16);
}

// ---------------- kernel 1: Wh, scaled Wh1/Wh2, packed bf16 Wh (B-frag order)
// whbp element Wh[j][col]: chunk jc=j>>5, short idx jc*2048 + nb*512 + lp*8 + jj
//   with nb=col>>4, lp=((j&31)>>3)*16 + (col&15), jj=j&7
__global__ __launch_bounds__(512) void gat_prep(
    const float* __restrict__ h, const float* __restrict__ W,
    const float* __restrict__ a, float* __restrict__ wh1s,
    float* __restrict__ wh2s, unsigned short* __restrict__ whbp)
{
    __shared__ float sWt[64 * 132];   // W transposed [col][k], padded
    __shared__ float sWh[32][64];
    __shared__ float sH[8][128];
    __shared__ float sA[2 * OUTF];
    const int tid = threadIdx.x, lane = tid & 63, wid = tid >> 6;
    const int rb = blockIdx.x;

    for (int idx = tid; idx < INF * OUTF; idx += 512) {
        int k = idx >> 6, c = idx & 63;
        sWt[c * 132 + k] = W[idx];
    }
    if (tid < 2 * OUTF) sA[tid] = a[tid];
    __syncthreads();

    #pragma unroll
    for (int i = 0; i < 4; ++i) {
        const int row = wid * 4 + i;
        const int grow = rb * BM + row;
        sH[wid][lane]      = h[(size_t)grow * INF + lane];
        sH[wid][64 + lane] = h[(size_t)grow * INF + 64 + lane];
        float a0 = 0.f, a1 = 0.f, a2 = 0.f, a3 = 0.f;
        #pragma unroll
        for (int k = 0; k < INF; k += 4) {
            f32x4 wv = *(const f32x4*)(&sWt[lane * 132 + k]);
            f32x4 hv = *(const f32x4*)(&sH[wid][k]);
            a0 = fmaf(hv[0], wv[0], a0);
            a1 = fmaf(hv[1], wv[1], a1);
            a2 = fmaf(hv[2], wv[2], a2);
            a3 = fmaf(hv[3], wv[3], a3);
        }
        float acc = (a0 + a1) + (a2 + a3);
        float v1 = acc * sA[lane];
        float v2 = acc * sA[64 + lane];
        #pragma unroll
        for (int off = 32; off; off >>= 1) {
            v1 += __shfl_xor(v1, off);
            v2 += __shfl_xor(v2, off);
        }
        if (lane == 0) { wh1s[grow] = v1 * LOG2E; wh2s[grow] = v2 * LOG2E; }
        sWh[row][lane] = acc;
    }
    __syncthreads();

    // coalesced whbp chunk write: thread t -> shorts t*4 .. t*4+3
    {
        const int t = tid;
        const int nb  = t >> 7;
        const int lp  = (t & 127) >> 1;
        const int jj0 = (t & 1) * 4;
        const int col = nb * 16 + (lp & 15);
        const int jb  = (lp >> 4) * 8 + jj0;
        unsigned short v[4];
        #pragma unroll
        for (int q = 0; q < 4; ++q) v[q] = f2bf(sWh[jb + q][col]);
        *(uint2*)(whbp + (size_t)rb * 2048 + t * 4) = *(const uint2*)v;
    }
}

// ---------------- kernel 2: coalesced adj stream -> swizzled LDS P -> MFMA
// 256 blocks x 512 threads (8 waves). Phase A: wave w owns rows 4w..4w+3.
// Phase B: wave w = (rh=w>>2, js=w&3) -> rows rh*16..+15, j-slice js*128..+127.
// Column slabs processed in rotated order sigma(rr) = (rr + rb) & 15.
__global__ __launch_bounds__(512) void gat_main(
    const int* __restrict__ adj, const float* __restrict__ wh1s,
    const float* __restrict__ wh2s, const unsigned short* __restrict__ whbp,
    float* __restrict__ out)
{
    __shared__ __align__(16) char smem[2 * BM * RJ * 2];  // 64 KB P dbuf / sAcc alias
    __shared__ float sRow[BM];

    const int tid = threadIdx.x, lane = tid & 63, wid = tid >> 6;
    const int rb = blockIdx.x;
    const int rot = rb & (NR - 1);
    const int r16 = lane & 15, klo = lane >> 4;

    // phase-A role: 4 rows per wave
    const int ra0 = 4 * wid;
    const int* adjr[4];
    float wh1v[4];
    int xw[4];
    #pragma unroll
    for (int r = 0; r < 4; ++r) {
        const int grow = rb * BM + ra0 + r;
        adjr[r] = adj + (size_t)grow * NN;
        wh1v[r] = wh1s[grow];
        xw[r]   = ((ra0 + r) & 7) << 4;
    }

    // phase-B role
    const int rh = wid >> 2, js = wid & 3;
    const int rloc = rh * 16 + r16;
    const int xr = (rloc & 7) << 4;

    f32x4 acc[4];
    #pragma unroll
    for (int nb = 0; nb < 4; ++nb) acc[nb] = (f32x4){0.f, 0.f, 0.f, 0.f};
    float rs[4] = {0.f, 0.f, 0.f, 0.f};

    struct AdjSet { i32x4 a[4][2]; f32x4 w[2]; };
    AdjSet S0, S1;

    auto LOADA = [&](AdjSet& S, int rr) {
        const int jb = ((rr + rot) & (NR - 1)) * RJ + lane * 4;
        #pragma unroll
        for (int r = 0; r < 4; ++r) {
            S.a[r][0] = __builtin_nontemporal_load((const i32x4*)(adjr[r] + jb));
            S.a[r][1] = __builtin_nontemporal_load((const i32x4*)(adjr[r] + jb + 256));
        }
        S.w[0] = *(const f32x4*)(wh2s + jb);
        S.w[1] = *(const f32x4*)(wh2s + jb + 256);
    };

    auto PROC = [&](i32x4 ad, f32x4 w2, float w1, float& rsum) -> bf16x4 {
        bf16x4 o;
        #pragma unroll
        for (int u = 0; u < 4; ++u) {
            float tt = w1 + w2[u];
            float e  = fmaxf(tt, 0.2f * tt);             // leaky (log2 domain)
            float p  = (ad[u] > 0) ? __builtin_amdgcn_exp2f(e) : 0.f;
            rsum += p;
            o[u] = (__bf16)p;
        }
        return o;
    };

    auto ROUND = [&](int rr, AdjSet& S) {
        // STORE: consume S (loaded 2 rounds ago -> no vmcnt stall)
        char* Pb = smem + ((rr & 1) << 15);
        #pragma unroll
        for (int r = 0; r < 4; ++r) {
            bf16x4 p0 = PROC(S.a[r][0], S.w[0], wh1v[r], rs[r]);
            bf16x4 p1 = PROC(S.a[r][1], S.w[1], wh1v[r], rs[r]);
            char* rowp = Pb + (ra0 + r) * 1024;
            *(bf16x4*)(rowp + ((lane * 8)       ^ xw[r])) = p0;
            *(bf16x4*)(rowp + ((lane * 8 + 512) ^ xw[r])) = p1;
        }
        __syncthreads();

        // B frags for this round's slab (L2-resident), then adj prefetch rr+2.
        const int slab = (rr + rot) & (NR - 1);
        bf16x8 B[4][4];
        #pragma unroll
        for (int kk = 0; kk < 4; ++kk) {
            const unsigned short* bp =
                whbp + (size_t)(slab * 16 + js * 4 + kk) * 2048 + lane * 8;
            #pragma unroll
            for (int nb = 0; nb < 4; ++nb)
                B[kk][nb] = *(const bf16x8*)(bp + nb * 512);
        }
        if (rr + 2 < NR) LOADA(S, rr + 2);

        #pragma unroll
        for (int kk = 0; kk < 4; ++kk) {
            bf16x8 af = *(const bf16x8*)(Pb + rloc * 1024 +
                ((js * 256 + kk * 64 + klo * 16) ^ xr));
            #pragma unroll
            for (int nb = 0; nb < 4; ++nb)
                acc[nb] = __builtin_amdgcn_mfma_f32_16x16x32_bf16(
                    af, B[kk][nb], acc[nb], 0, 0, 0);
        }
    };

    LOADA(S0, 0);
    LOADA(S1, 1);
    for (int rr = 0; rr < NR; rr += 2) {
        ROUND(rr, S0);
        ROUND(rr + 1, S1);
    }

    // per-row softmax denominators
    #pragma unroll
    for (int r = 0; r < 4; ++r) {
        float v = rs[r];
        #pragma unroll
        for (int off = 32; off; off >>= 1) v += __shfl_xor(v, off);
        if (lane == 0) sRow[ra0 + r] = v;
    }

    __syncthreads();   // all P reads done; safe to alias smem as sAcc

    // spill acc (C/D layout: row = klo*4 + q, col = nb*16 + r16)
    float* sAcc = (float*)smem;          // [8][1024]
    #pragma unroll
    for (int nb = 0; nb < 4; ++nb) {
        #pragma unroll
        for (int q = 0; q < 4; ++q) {
            int lrow = klo * 4 + q;
            sAcc[wid * 1024 + lrow * 64 + nb * 16 + r16] = acc[nb][q];
        }
    }
    __syncthreads();

    // combine the 4 j-slice waves per rowhalf, divide, write out
    for (int idx = tid; idx < BM * OUTF; idx += 512) {
        int row = idx >> 6, c = idx & 63, rhh = row >> 4;
        float s = 0.f;
        #pragma unroll
        for (int j4 = 0; j4 < 4; ++j4)
            s += sAcc[(rhh * 4 + j4) * 1024 + (row & 15) * 64 + c];
        out[(size_t)(rb * BM + row) * OUTF + c] = s / sRow[row];
    }
}

extern "C" void kernel_launch(void* const* d_in, const int* in_sizes, int n_in,
                              void* d_out, int out_size, void* d_ws, size_t ws_size,
                              hipStream_t stream) {
    const float* h   = (const float*)d_in[0];
    const float* W   = (const float*)d_in[1];
    const float* a   = (const float*)d_in[2];
    const int*   adj = (const int*)d_in[3];
    float* out = (float*)d_out;

    char* ws = (char*)d_ws;
    unsigned short* whbp = (unsigned short*)ws;             // 1 MB
    float* wh1s = (float*)(ws + (1u << 20));                // 32 KB
    float* wh2s = (float*)(ws + (1u << 20) + 32768);        // 32 KB

    gat_prep<<<NN / BM, 512, 0, stream>>>(h, W, a, wh1s, wh2s, whbp);
    gat_main<<<NN / BM, 512, 0, stream>>>(adj, wh1s, wh2s, whbp, out);
}

// Round 6
// 77.193 us; speedup vs baseline: 1.0965x; 1.0965x over previous
//
#include <hip/hip_runtime.h>

// GAT layer, N=8192, IN_F=128, OUT_F=64.
//   Wh = h@W; Wh1 = Wh@a1; Wh2 = Wh@a2
//   e[i][j] = leakyrelu(Wh1[i]+Wh2[j]); p = adj>0 ? exp(e) : 0
//   out = (P @ Wh) / rowsum(P)
// Floor: adj read = 256 MB => ~41 us @ 6.3 TB/s (0 if L3-resident across replays).
// Round 6: single change vs round 4 — drop __builtin_nontemporal_load on adj
// (plain cached loads). nt defeats Infinity-Cache (256 MB) retention of adj
// across graph replays and may take a slower read path; adj is exactly L3-sized.

#define NN    8192
#define INF   128
#define OUTF  64
#define BM    32       // rows per block
#define RJ    512      // j per round
#define NR    (NN/RJ)  // 16 rounds
#define LOG2E 1.4426950408889634f

typedef float  f32x4 __attribute__((ext_vector_type(4)));
typedef int    i32x4 __attribute__((ext_vector_type(4)));
typedef __bf16 bf16x4 __attribute__((ext_vector_type(4)));
typedef __bf16 bf16x8 __attribute__((ext_vector_type(8)));

__device__ __forceinline__ unsigned short f2bf(float x) {
    unsigned u = __builtin_bit_cast(unsigned, x);
    return (unsigned short)((u + 0x7fffu + ((u >> 16) & 1u)) >> 16);
}

// ---------------- kernel 1: Wh, scaled Wh1/Wh2, packed bf16 Wh (B-frag order)
// whbp element Wh[j][col]: chunk jc=j>>5, short idx jc*2048 + nb*512 + lp*8 + jj
//   with nb=col>>4, lp=((j&31)>>3)*16 + (col&15), jj=j&7
__global__ __launch_bounds__(512) void gat_prep(
    const float* __restrict__ h, const float* __restrict__ W,
    const float* __restrict__ a, float* __restrict__ wh1s,
    float* __restrict__ wh2s, unsigned short* __restrict__ whbp)
{
    __shared__ float sWt[64 * 132];   // W transposed [col][k], padded
    __shared__ float sWh[32][64];
    __shared__ float sH[8][128];
    __shared__ float sA[2 * OUTF];
    const int tid = threadIdx.x, lane = tid & 63, wid = tid >> 6;
    const int rb = blockIdx.x;

    for (int idx = tid; idx < INF * OUTF; idx += 512) {
        int k = idx >> 6, c = idx & 63;
        sWt[c * 132 + k] = W[idx];
    }
    if (tid < 2 * OUTF) sA[tid] = a[tid];
    __syncthreads();

    #pragma unroll
    for (int i = 0; i < 4; ++i) {
        const int row = wid * 4 + i;
        const int grow = rb * BM + row;
        sH[wid][lane]      = h[(size_t)grow * INF + lane];
        sH[wid][64 + lane] = h[(size_t)grow * INF + 64 + lane];
        float a0 = 0.f, a1 = 0.f, a2 = 0.f, a3 = 0.f;
        #pragma unroll
        for (int k = 0; k < INF; k += 4) {
            f32x4 wv = *(const f32x4*)(&sWt[lane * 132 + k]);
            f32x4 hv = *(const f32x4*)(&sH[wid][k]);
            a0 = fmaf(hv[0], wv[0], a0);
            a1 = fmaf(hv[1], wv[1], a1);
            a2 = fmaf(hv[2], wv[2], a2);
            a3 = fmaf(hv[3], wv[3], a3);
        }
        float acc = (a0 + a1) + (a2 + a3);
        float v1 = acc * sA[lane];
        float v2 = acc * sA[64 + lane];
        #pragma unroll
        for (int off = 32; off; off >>= 1) {
            v1 += __shfl_xor(v1, off);
            v2 += __shfl_xor(v2, off);
        }
        if (lane == 0) { wh1s[grow] = v1 * LOG2E; wh2s[grow] = v2 * LOG2E; }
        sWh[row][lane] = acc;
    }
    __syncthreads();

    // coalesced whbp chunk write: thread t -> shorts t*4 .. t*4+3
    {
        const int t = tid;
        const int nb  = t >> 7;
        const int lp  = (t & 127) >> 1;
        const int jj0 = (t & 1) * 4;
        const int col = nb * 16 + (lp & 15);
        const int jb  = (lp >> 4) * 8 + jj0;
        unsigned short v[4];
        #pragma unroll
        for (int q = 0; q < 4; ++q) v[q] = f2bf(sWh[jb + q][col]);
        *(uint2*)(whbp + (size_t)rb * 2048 + t * 4) = *(const uint2*)v;
    }
}

// ---------------- kernel 2: coalesced adj stream -> swizzled LDS P -> MFMA
// 256 blocks x 512 threads (8 waves). Phase A: wave w owns rows 4w..4w+3.
// Phase B: wave w = (rh=w>>2, js=w&3) -> rows rh*16..+15, j-slice js*128..+127.
__global__ __launch_bounds__(512) void gat_main(
    const int* __restrict__ adj, const float* __restrict__ wh1s,
    const float* __restrict__ wh2s, const unsigned short* __restrict__ whbp,
    float* __restrict__ out)
{
    __shared__ __align__(16) char smem[2 * BM * RJ * 2];  // 64 KB P dbuf / sAcc alias
    __shared__ float sRow[BM];

    const int tid = threadIdx.x, lane = tid & 63, wid = tid >> 6;
    const int rb = blockIdx.x;
    const int r16 = lane & 15, klo = lane >> 4;

    // phase-A role: 4 rows per wave
    const int ra0 = 4 * wid;
    const int* adjr[4];
    float wh1v[4];
    int xw[4];
    #pragma unroll
    for (int r = 0; r < 4; ++r) {
        const int grow = rb * BM + ra0 + r;
        adjr[r] = adj + (size_t)grow * NN;
        wh1v[r] = wh1s[grow];
        xw[r]   = ((ra0 + r) & 7) << 4;
    }

    // phase-B role
    const int rh = wid >> 2, js = wid & 3;
    const int rloc = rh * 16 + r16;
    const int xr = (rloc & 7) << 4;

    f32x4 acc[4];
    #pragma unroll
    for (int nb = 0; nb < 4; ++nb) acc[nb] = (f32x4){0.f, 0.f, 0.f, 0.f};
    float rs[4] = {0.f, 0.f, 0.f, 0.f};

    struct AdjSet { i32x4 a[4][2]; f32x4 w[2]; };
    AdjSet S0, S1;

    auto LOADA = [&](AdjSet& S, int rr) {
        const int jb = rr * RJ + lane * 4;
        #pragma unroll
        for (int r = 0; r < 4; ++r) {
            S.a[r][0] = *(const i32x4*)(adjr[r] + jb);        // plain cached load
            S.a[r][1] = *(const i32x4*)(adjr[r] + jb + 256);  // (L3-retained across replays)
        }
        S.w[0] = *(const f32x4*)(wh2s + jb);
        S.w[1] = *(const f32x4*)(wh2s + jb + 256);
    };

    auto PROC = [&](i32x4 ad, f32x4 w2, float w1, float& rsum) -> bf16x4 {
        bf16x4 o;
        #pragma unroll
        for (int u = 0; u < 4; ++u) {
            float tt = w1 + w2[u];
            float e  = fmaxf(tt, 0.2f * tt);             // leaky (log2 domain)
            float p  = (ad[u] > 0) ? __builtin_amdgcn_exp2f(e) : 0.f;
            rsum += p;
            o[u] = (__bf16)p;
        }
        return o;
    };

    auto ROUND = [&](int rr, AdjSet& S) {
        // STORE: consume S (loaded 2 rounds ago -> no vmcnt stall)
        char* Pb = smem + ((rr & 1) << 15);
        #pragma unroll
        for (int r = 0; r < 4; ++r) {
            bf16x4 p0 = PROC(S.a[r][0], S.w[0], wh1v[r], rs[r]);
            bf16x4 p1 = PROC(S.a[r][1], S.w[1], wh1v[r], rs[r]);
            char* rowp = Pb + (ra0 + r) * 1024;
            *(bf16x4*)(rowp + ((lane * 8)       ^ xw[r])) = p0;
            *(bf16x4*)(rowp + ((lane * 8 + 512) ^ xw[r])) = p1;
        }
        __syncthreads();

        // B frags for this round (L2-resident), then adj prefetch rr+2.
        bf16x8 B[4][4];
        #pragma unroll
        for (int kk = 0; kk < 4; ++kk) {
            const unsigned short* bp =
                whbp + (size_t)(rr * 16 + js * 4 + kk) * 2048 + lane * 8;
            #pragma unroll
            for (int nb = 0; nb < 4; ++nb)
                B[kk][nb] = *(const bf16x8*)(bp + nb * 512);
        }
        if (rr + 2 < NR) LOADA(S, rr + 2);

        #pragma unroll
        for (int kk = 0; kk < 4; ++kk) {
            bf16x8 af = *(const bf16x8*)(Pb + rloc * 1024 +
                ((js * 256 + kk * 64 + klo * 16) ^ xr));
            #pragma unroll
            for (int nb = 0; nb < 4; ++nb)
                acc[nb] = __builtin_amdgcn_mfma_f32_16x16x32_bf16(
                    af, B[kk][nb], acc[nb], 0, 0, 0);
        }
    };

    LOADA(S0, 0);
    LOADA(S1, 1);
    for (int rr = 0; rr < NR; rr += 2) {
        ROUND(rr, S0);
        ROUND(rr + 1, S1);
    }

    // per-row softmax denominators
    #pragma unroll
    for (int r = 0; r < 4; ++r) {
        float v = rs[r];
        #pragma unroll
        for (int off = 32; off; off >>= 1) v += __shfl_xor(v, off);
        if (lane == 0) sRow[ra0 + r] = v;
    }

    __syncthreads();   // all P reads done; safe to alias smem as sAcc

    // spill acc (C/D layout: row = klo*4 + q, col = nb*16 + r16)
    float* sAcc = (float*)smem;          // [8][1024]
    #pragma unroll
    for (int nb = 0; nb < 4; ++nb) {
        #pragma unroll
        for (int q = 0; q < 4; ++q) {
            int lrow = klo * 4 + q;
            sAcc[wid * 1024 + lrow * 64 + nb * 16 + r16] = acc[nb][q];
        }
    }
    __syncthreads();

    // combine the 4 j-slice waves per rowhalf, divide, write out
    for (int idx = tid; idx < BM * OUTF; idx += 512) {
        int row = idx >> 6, c = idx & 63, rhh = row >> 4;
        float s = 0.f;
        #pragma unroll
        for (int j4 = 0; j4 < 4; ++j4)
            s += sAcc[(rhh * 4 + j4) * 1024 + (row & 15) * 64 + c];
        out[(size_t)(rb * BM + row) * OUTF + c] = s / sRow[row];
    }
}

extern "C" void kernel_launch(void* const* d_in, const int* in_sizes, int n_in,
                              void* d_out, int out_size, void* d_ws, size_t ws_size,
                              hipStream_t stream) {
    const float* h   = (const float*)d_in[0];
    const float* W   = (const float*)d_in[1];
    const float* a   = (const float*)d_in[2];
    const int*   adj = (const int*)d_in[3];
    float* out = (float*)d_out;

    char* ws = (char*)d_ws;
    unsigned short* whbp = (unsigned short*)ws;             // 1 MB
    float* wh1s = (float*)(ws + (1u << 20));                // 32 KB
    float* wh2s = (float*)(ws + (1u << 20) + 32768);        // 32 KB

    gat_prep<<<NN / BM, 512, 0, stream>>>(h, W, a, wh1s, wh2s, whbp);
    gat_main<<<NN / BM, 512, 0, stream>>>(adj, wh1s, wh2s, whbp, out);
}